// Round 5
// baseline (91.358 us; speedup 1.0000x reference)
//
#include <hip/hip_runtime.h>
#include <cfloat>

#define BLOCK 256
#define RPT 8            // rows per thread -> 2048 rows per block
#define PAIRS (RPT / 2)  // rows packed 2-per-float2 for v_pk_fma_f32
#define SLICES 64        // column slices per side

typedef float v2f __attribute__((ext_vector_type(2)));

// blockIdx.z==0: rows=A (true), cols=B (pred)  -> sbuf[0]  ("mins")
// blockIdx.z==1: rows=B (pred), cols=A (true)  -> sbuf[1]  ("mins_seeds")
// Minimize s = ||y||^2/2 - x.y  (3 pk_fma + 2 min per 2 pairs); d2 = ||x||^2 + 2s
// reconstructed in finalize. No atomics: each (slice, row) partial min is
// written raw to sbuf; finalize reduces over slices. Empty slices still write
// FLT_MAX (ws is poisoned 0xAA = small NEGATIVE float -> would win a min).
__global__ __launch_bounds__(BLOCK) void pairmin_kernel(
    const float* __restrict__ A, const float* __restrict__ B,
    float* __restrict__ hdr, float* __restrict__ sbuf,
    int n, int m, int colsPerSlice, int strideRows)
{
    // zero the scalar-accumulator header here (saves a memset launch);
    // visible to finalize_kernel via the kernel-boundary.
    if (blockIdx.x == 0 && blockIdx.y == 0 && blockIdx.z == 0 && threadIdx.x < 8)
        hdr[threadIdx.x] = 0.f;

    const float* X; const float* Y; int nx_, ny_;
    float* out_slice;
    if (blockIdx.z == 0) { X = A; Y = B; nx_ = n; ny_ = m; out_slice = sbuf; }
    else                 { X = B; Y = A; nx_ = m; ny_ = n;
                           out_slice = sbuf + (size_t)SLICES * strideRows; }
    out_slice += (size_t)blockIdx.y * strideRows;

    const int tid = threadIdx.x;
    const int rowBase = blockIdx.x * (BLOCK * RPT);
    if (rowBase >= nx_) return;                      // block-uniform exit

    const int colBeg = blockIdx.y * colsPerSlice;
    const int colEnd = min(colBeg + colsPerSlice, ny_);

    v2f nrx[PAIRS], nry[PAIRS], nrz[PAIRS], mn[PAIRS];
#pragma unroll
    for (int p = 0; p < PAIRS; ++p) {
        const int r0 = rowBase + tid + (2 * p) * BLOCK;
        const int r1 = r0 + BLOCK;
        const int rr0 = (r0 < nx_) ? r0 : 0;
        const int rr1 = (r1 < nx_) ? r1 : 0;
        nrx[p] = (v2f){-X[3 * rr0 + 0], -X[3 * rr1 + 0]};
        nry[p] = (v2f){-X[3 * rr0 + 1], -X[3 * rr1 + 1]};
        nrz[p] = (v2f){-X[3 * rr0 + 2], -X[3 * rr1 + 2]};
        mn[p] = (v2f){FLT_MAX, FLT_MAX};
    }

    __shared__ float4 cols[BLOCK];
    for (int c0 = colBeg; c0 < colEnd; c0 += BLOCK) {
        const int cnt = min(BLOCK, colEnd - c0);
        if (tid < cnt) {
            const int c = c0 + tid;
            const float yx = Y[3 * c + 0];
            const float yy = Y[3 * c + 1];
            const float yz = Y[3 * c + 2];
            const float halfny = 0.5f * fmaf(yx, yx, fmaf(yy, yy, yz * yz));
            cols[tid] = make_float4(yx, yy, yz, halfny);
        }
        __syncthreads();
#pragma unroll 4
        for (int j = 0; j < cnt; ++j) {
            const float4 cc = cols[j];   // wave-uniform broadcast, conflict-free
            const v2f cx = cc.x, cy = cc.y, cz = cc.z, cw = cc.w;  // splats
#pragma unroll
            for (int p = 0; p < PAIRS; ++p) {
                v2f s = __builtin_elementwise_fma(nrz[p], cz, cw);
                s = __builtin_elementwise_fma(nry[p], cy, s);
                s = __builtin_elementwise_fma(nrx[p], cx, s);
                mn[p] = __builtin_elementwise_min(mn[p], s);
            }
        }
        __syncthreads();
    }

#pragma unroll
    for (int p = 0; p < PAIRS; ++p) {
        const int r0 = rowBase + tid + (2 * p) * BLOCK;
        const int r1 = r0 + BLOCK;
        if (r0 < nx_) out_slice[r0] = mn[p].x;
        if (r1 < nx_) out_slice[r1] = mn[p].y;
    }
}

// One row of each side per thread. ws header: hdr[0]=sumA, hdr[1]=sumB,
// hdr[2]=ticket. out layout: [loss+loss_seeds, mins_seeds(m), loss, loss_seeds]
__global__ __launch_bounds__(256) void finalize_kernel(
    const float* __restrict__ A, const float* __restrict__ B,
    const float* __restrict__ sbuf, float* __restrict__ hdr,
    float* __restrict__ out, int n, int m, int strideRows)
{
    const int i = blockIdx.x * 256 + threadIdx.x;
    float sa = 0.f, sb = 0.f;
    if (i < n) {
        float s = FLT_MAX;
        const float* p = sbuf + i;
#pragma unroll 8
        for (int k = 0; k < SLICES; ++k) s = fminf(s, p[(size_t)k * strideRows]);
        const float ax = A[3 * i], ay = A[3 * i + 1], az = A[3 * i + 2];
        const float nrm = fmaf(ax, ax, fmaf(ay, ay, az * az));
        sa = sqrtf(fmaxf(fmaf(2.f, s, nrm), 0.f));
    }
    if (i < m) {
        float s = FLT_MAX;
        const float* p = sbuf + (size_t)SLICES * strideRows + i;
#pragma unroll 8
        for (int k = 0; k < SLICES; ++k) s = fminf(s, p[(size_t)k * strideRows]);
        const float bx = B[3 * i], by = B[3 * i + 1], bz = B[3 * i + 2];
        const float nrm = fmaf(bx, bx, fmaf(by, by, bz * bz));
        const float v = sqrtf(fmaxf(fmaf(2.f, s, nrm), 0.f));
        out[1 + i] = v;                  // mins_seeds
        sb = v;
    }

#pragma unroll
    for (int off = 32; off > 0; off >>= 1) {
        sa += __shfl_down(sa, off, 64);
        sb += __shfl_down(sb, off, 64);
    }
    __shared__ float reda[4], redb[4];
    const int wave = threadIdx.x >> 6;
    const int lane = threadIdx.x & 63;
    if (lane == 0) { reda[wave] = sa; redb[wave] = sb; }
    __syncthreads();

    if (threadIdx.x == 0) {
        const float ta = reda[0] + reda[1] + reda[2] + reda[3];
        const float tb = redb[0] + redb[1] + redb[2] + redb[3];
        atomicAdd(&hdr[0], ta);
        atomicAdd(&hdr[1], tb);
        __threadfence();
        const unsigned ticket = atomicAdd((unsigned*)&hdr[2], 1u);
        if (ticket == (unsigned)(gridDim.x - 1)) {
            const float fa = atomicAdd(&hdr[0], 0.f);   // coherent read of totals
            const float fb = atomicAdd(&hdr[1], 0.f);
            const float loss = fa / (float)n;
            const float loss_seeds = fb / (float)m;
            out[0] = loss + loss_seeds;
            out[1 + m] = loss;
            out[2 + m] = loss_seeds;
        }
    }
}

extern "C" void kernel_launch(void* const* d_in, const int* in_sizes, int n_in,
                              void* d_out, int out_size, void* d_ws, size_t ws_size,
                              hipStream_t stream) {
    const int n = in_sizes[0] / 3;   // true_pos count
    const int m = in_sizes[1] / 3;   // pred_pos count
    const float* A = (const float*)d_in[0];
    const float* B = (const float*)d_in[1];
    float* out = (float*)d_out;

    float* hdr = (float*)d_ws;                        // 64-byte header region
    float* sbuf = (float*)((char*)d_ws + 64);         // 2*SLICES*maxnm floats

    const int maxnm = (n > m) ? n : m;
    const int gx = (maxnm + BLOCK * RPT - 1) / (BLOCK * RPT);
    const int colsPerSlice = (maxnm + SLICES - 1) / SLICES;
    dim3 grid(gx, SLICES, 2);
    pairmin_kernel<<<grid, BLOCK, 0, stream>>>(A, B, hdr, sbuf, n, m,
                                               colsPerSlice, maxnm);

    const int fb = (maxnm + 255) / 256;
    finalize_kernel<<<fb, 256, 0, stream>>>(A, B, sbuf, hdr, out, n, m, maxnm);
}